// Round 13
// baseline (164.266 us; speedup 1.0000x reference)
//
#include <hip/hip_runtime.h>

#define N_NODES   100000
#define N_EDGES   1600000
#define N_CLIQUES 250000
#define FIXSCALE  8388608.0f              // 2^23
#define INVSCALE  1.1920928955078125e-7f  // 2^-23

typedef unsigned short ushort8v __attribute__((ext_vector_type(8)));
typedef __bf16 bf16x8 __attribute__((ext_vector_type(8)));
typedef float f32x4 __attribute__((ext_vector_type(4)));
typedef float f32x2 __attribute__((ext_vector_type(2)));

__device__ __forceinline__ float bf2f(unsigned short u) {
    return __uint_as_float(((unsigned int)u) << 16);
}
__device__ __forceinline__ unsigned short f2bf(float f) {
    unsigned int u = __float_as_uint(f);
    u += 0x7FFFu + ((u >> 16) & 1u);
    return (unsigned short)(u >> 16);
}

// ---- prep: W [k][col] f32  ->  wt bf16 [t][col][k] ----
__global__ __launch_bounds__(256) void prep_weights(
    const float* __restrict__ Qw, const float* __restrict__ Kw,
    const float* __restrict__ Vw, unsigned short* __restrict__ wt)
{
    int idx = blockIdx.x * 256 + threadIdx.x;      // 3*128*128 = 49152
    int t = idx >> 14;
    int rem = idx & 16383;
    int col = rem >> 7;
    int k = rem & 127;
    const float* W = (t == 0) ? Qw : ((t == 1) ? Kw : Vw);
    wt[idx] = f2bf(W[k * 128 + col]);              // wt[t][col][k]
}

// ---- Projection via MFMA -> qkv8 fp8-e4m3, FRAGMENT-PERMUTED layout ----
// 512 threads = 8 waves = 128 nodes/block; 32KB W tile serves 2x nodes vs r10.
// Within each t-region of a node, byte (arow*8 + c) holds output col (c*16+arow).
// Same permutation for q,k,v => the clique contraction (sum over d) is invariant.
__global__ __launch_bounds__(512, 6) void proj_mfma(
    const float* __restrict__ x,
    const unsigned short* __restrict__ wt,   // bf16 [3][col 128][k 128]
    const float* __restrict__ Qb, const float* __restrict__ Kb,
    const float* __restrict__ Vb,
    unsigned char* __restrict__ qkv8)
{
    __shared__ unsigned short wS[128 * 128];  // 32KB W tile, XOR-swizzled chunks

    const int tid  = threadIdx.x;
    const int lane = tid & 63;
    const int w    = tid >> 6;        // wave 0..7
    const int node0 = blockIdx.x * 128;
    const int arow = lane & 15;
    const int kg   = lane >> 4;

    bf16x8 afrag[4];
    const int myNode = node0 + w * 16 + arow;
    const bool valid = myNode < N_NODES;
    const float* xrow = x + (size_t)myNode * 128;
    #pragma unroll
    for (int kt = 0; kt < 4; ++kt) {
        float4 v0, v1;
        const int kbase = kt * 32 + kg * 8;
        if (valid) {
            v0 = *(const float4*)(xrow + kbase);
            v1 = *(const float4*)(xrow + kbase + 4);
        } else {
            v0.x = v0.y = v0.z = v0.w = 0.f;
            v1.x = v1.y = v1.z = v1.w = 0.f;
        }
        ushort8v u;
        u[0] = f2bf(v0.x); u[1] = f2bf(v0.y); u[2] = f2bf(v0.z); u[3] = f2bf(v0.w);
        u[4] = f2bf(v1.x); u[5] = f2bf(v1.y); u[6] = f2bf(v1.z); u[7] = f2bf(v1.w);
        afrag[kt] = __builtin_bit_cast(bf16x8, u);
    }

    for (int t = 0; t < 3; ++t) {
        __syncthreads();   // protect wS from previous t's MFMA readers
        {
            const unsigned short* src = wt + t * 16384;
            #pragma unroll
            for (int it = 0; it < 4; ++it) {
                int i   = tid + it * 512;      // 2048 chunks / 512 thr = 4 each
                int col = i >> 4;
                int ko  = i & 15;
                *(ushort8v*)&wS[col * 128 + (ko ^ (col & 7)) * 8] =
                    *(const ushort8v*)(src + i * 8);
            }
        }
        // bias for this t only (8 regs live)
        const float* Bp = (t == 0) ? Qb : ((t == 1) ? Kb : Vb);
        float biasr[8];
        #pragma unroll
        for (int c = 0; c < 8; ++c) biasr[c] = Bp[c * 16 + arow];
        __syncthreads();

        f32x4 acc[8];
        #pragma unroll
        for (int c = 0; c < 8; ++c) acc[c] = (f32x4){0.f, 0.f, 0.f, 0.f};

        #pragma unroll
        for (int kt = 0; kt < 4; ++kt) {
            const int chunk = kt * 4 + kg;
            #pragma unroll
            for (int c = 0; c < 8; ++c) {
                const int col = c * 16 + arow;
                ushort8v bu = *(const ushort8v*)&wS[col * 128 + (chunk ^ (col & 7)) * 8];
                acc[c] = __builtin_amdgcn_mfma_f32_16x16x32_bf16(
                    afrag[kt], __builtin_bit_cast(bf16x8, bu), acc[c], 0, 0, 0);
            }
        }

        // Direct store: D row (node) = w*16 + kg*4 + r; lane holds cols c*16+arow.
        #pragma unroll
        for (int r = 0; r < 4; ++r) {
            int node = node0 + w * 16 + kg * 4 + r;
            if (node < N_NODES) {
                int lo0 = __builtin_amdgcn_cvt_pk_fp8_f32(
                    acc[0][r] + biasr[0], acc[1][r] + biasr[1], 0, false);
                unsigned int w0 = (unsigned int)__builtin_amdgcn_cvt_pk_fp8_f32(
                    acc[2][r] + biasr[2], acc[3][r] + biasr[3], lo0, true);
                int lo1 = __builtin_amdgcn_cvt_pk_fp8_f32(
                    acc[4][r] + biasr[4], acc[5][r] + biasr[5], 0, false);
                unsigned int w1 = (unsigned int)__builtin_amdgcn_cvt_pk_fp8_f32(
                    acc[6][r] + biasr[6], acc[7][r] + biasr[7], lo1, true);
                uint2 o; o.x = w0; o.y = w1;
                *(uint2*)(qkv8 + (size_t)node * 384 + t * 128 + arow * 8) = o;
            }
        }
    }
}

#define DEC4(w_, a_) { f32x2 lo_ = __builtin_amdgcn_cvt_pk_f32_fp8((int)(w_), false); \
                       f32x2 hi_ = __builtin_amdgcn_cvt_pk_f32_fp8((int)(w_), true);  \
                       a_[0] = lo_[0]; a_[1] = lo_[1]; a_[2] = hi_[0]; a_[3] = hi_[1]; }

// ---- Clique contraction (fp8 gather) + fused scatter, ALL-INT atomics ----
// A1: uint fixed-point into a1u (750K). A0: uint fixed-point into 8 spread
// copies (1.5M). Int RMW rate ~21.9/ns vs fp32's 19.0/ns (r12 measured).
__global__ __launch_bounds__(256) void clique_kernel(
    const unsigned char* __restrict__ qkv8,
    const int* __restrict__ tci,      // [3][N_CLIQUES]
    const int* __restrict__ d1row1,   // [3*N_CLIQUES] clique -> edge ids
    const int* __restrict__ d0row1,   // [2*N_EDGES]   edge -> node ids
    unsigned int* __restrict__ a1u,   // [N_EDGES] fixed-point A1
    float* __restrict__ outA2,
    unsigned int* __restrict__ a0c)   // [8][N_NODES] fixed-point A0
{
    const int tid = threadIdx.x;
    const int lane8 = tid & 7;
    const int cliq = (blockIdx.x * 256 + tid) >> 3;
    if (cliq >= N_CLIQUES) return;

    const int ni = tci[cliq];
    const int nj = tci[N_CLIQUES + cliq];
    const int nk = tci[2 * N_CLIQUES + cliq];
    const int d0 = lane8 * 16;

    const unsigned char* bi = qkv8 + (size_t)ni * 384 + d0;
    const unsigned char* bj = qkv8 + (size_t)nj * 384 + d0;
    const unsigned char* bk = qkv8 + (size_t)nk * 384 + d0;

    const uint4 rQi = *(const uint4*)(bi);
    const uint4 rKi = *(const uint4*)(bi + 128);
    const uint4 rVi = *(const uint4*)(bi + 256);
    const uint4 rQj = *(const uint4*)(bj);
    const uint4 rKj = *(const uint4*)(bj + 128);
    const uint4 rVj = *(const uint4*)(bj + 256);
    const uint4 rQk = *(const uint4*)(bk);
    const uint4 rKk = *(const uint4*)(bk + 128);
    const uint4 rVk = *(const uint4*)(bk + 256);

    float s = 0.f;
    #pragma unroll
    for (int c = 0; c < 4; ++c) {
        unsigned int wQi = ((const unsigned int*)&rQi)[c];
        unsigned int wKi = ((const unsigned int*)&rKi)[c];
        unsigned int wVi = ((const unsigned int*)&rVi)[c];
        unsigned int wQj = ((const unsigned int*)&rQj)[c];
        unsigned int wKj = ((const unsigned int*)&rKj)[c];
        unsigned int wVj = ((const unsigned int*)&rVj)[c];
        unsigned int wQk = ((const unsigned int*)&rQk)[c];
        unsigned int wKk = ((const unsigned int*)&rKk)[c];
        unsigned int wVk = ((const unsigned int*)&rVk)[c];
        float qi_[4], ki_[4], vi_[4], qj_[4], kj_[4], vj_[4], qk_[4], kk_[4], vk_[4];
        DEC4(wQi, qi_); DEC4(wKi, ki_); DEC4(wVi, vi_);
        DEC4(wQj, qj_); DEC4(wKj, kj_); DEC4(wVj, vj_);
        DEC4(wQk, qk_); DEC4(wKk, kk_); DEC4(wVk, vk_);
        #pragma unroll
        for (int d = 0; d < 4; ++d) {
            s = fmaf(qi_[d], fmaf(kj_[d], vk_[d], kk_[d] * vj_[d]), s);
            s = fmaf(qj_[d], fmaf(kk_[d], vi_[d], ki_[d] * vk_[d]), s);
            s = fmaf(qk_[d], fmaf(ki_[d], vj_[d], kj_[d] * vi_[d]), s);
        }
    }
    s += __shfl_xor(s, 1);
    s += __shfl_xor(s, 2);
    s += __shfl_xor(s, 4);

    float score = expf(s * (1.0f / 24.0f));
    if (lane8 == 0) outA2[cliq] = score;
    if (lane8 < 3) {
        int e = d1row1[3 * cliq + lane8];
        unsigned int fx = (unsigned int)__float2uint_rn(score * FIXSCALE);
        atomicAdd(a1u + e, fx);
        int2 tg = *(const int2*)(d0row1 + 2 * (size_t)e);
        unsigned int* base = a0c + (size_t)(cliq & 7) * N_NODES;
        atomicAdd(base + tg.x, fx);
        atomicAdd(base + tg.y, fx);
    }
}

// ---- Decode A1 fixed-point -> float (pure overwrite of outA1) ----
__global__ __launch_bounds__(256) void decodeA1_kernel(
    const unsigned int* __restrict__ a1u, float* __restrict__ outA1)
{
    int e4 = blockIdx.x * 256 + threadIdx.x;     // 400000 threads, 4 edges each
    if (e4 * 4 < N_EDGES) {
        uint4 v = *(const uint4*)(a1u + e4 * 4);
        float4 o;
        o.x = (float)v.x * INVSCALE;
        o.y = (float)v.y * INVSCALE;
        o.z = (float)v.z * INVSCALE;
        o.w = (float)v.w * INVSCALE;
        *(float4*)(outA1 + e4 * 4) = o;
    }
}

// ---- Combine the 8 A0 fixed-point copies, decode to float ----
__global__ __launch_bounds__(256) void combineA0_kernel(
    const unsigned int* __restrict__ a0c, float* __restrict__ outA0)
{
    int n = blockIdx.x * 256 + threadIdx.x;
    if (n < N_NODES) {
        unsigned int s = 0;
        #pragma unroll
        for (int c = 0; c < 8; ++c) s += a0c[(size_t)c * N_NODES + n];
        outA0[n] = (float)s * INVSCALE;
    }
}

extern "C" void kernel_launch(void* const* d_in, const int* in_sizes, int n_in,
                              void* d_out, int out_size, void* d_ws, size_t ws_size,
                              hipStream_t stream)
{
    const float* x  = (const float*)d_in[0];
    const int*   d0i = (const int*)d_in[2];
    const int*   tci = (const int*)d_in[3];
    const int*   d1i = (const int*)d_in[4];
    const float* Qw = (const float*)d_in[5];
    const float* Qb = (const float*)d_in[6];
    const float* Kw = (const float*)d_in[7];
    const float* Kb = (const float*)d_in[8];
    const float* Vw = (const float*)d_in[9];
    const float* Vb = (const float*)d_in[10];

    const int* d0row1 = d0i + 2 * (size_t)N_EDGES;
    const int* d1row1 = d1i + 3 * (size_t)N_CLIQUES;

    // ws: qkv8 38.4MB | wt 96KB | a1u u32 6.4MB | a0c u32 [8][N_NODES] 3.2MB
    const size_t QKV_B = (size_t)N_NODES * 384;
    const size_t WT_B  = 3 * 128 * 128 * 2;
    const size_t A1U_B = (size_t)N_EDGES * 4;
    unsigned char* qkv8 = (unsigned char*)d_ws;
    unsigned short* wt  = (unsigned short*)(qkv8 + QKV_B);
    unsigned int* a1u = (unsigned int*)(qkv8 + QKV_B + WT_B);
    unsigned int* a0c = (unsigned int*)(qkv8 + QKV_B + WT_B + A1U_B);

    // outputs: FLOAT32, concatenated (diagA0, diagA1, diagA2)
    float* outA0 = (float*)d_out;
    float* outA1 = outA0 + N_NODES;
    float* outA2 = outA0 + N_NODES + N_EDGES;

    hipMemsetAsync(a1u, 0, A1U_B, stream);
    hipMemsetAsync(a0c, 0, (size_t)8 * N_NODES * 4, stream);
    prep_weights<<<192, 256, 0, stream>>>(Qw, Kw, Vw, wt);
    proj_mfma<<<(N_NODES + 127) / 128, 512, 0, stream>>>(x, wt, Qb, Kb, Vb, qkv8);
    clique_kernel<<<(N_CLIQUES * 8 + 255) / 256, 256, 0, stream>>>(
        qkv8, tci, d1row1, d0row1, a1u, outA2, a0c);
    decodeA1_kernel<<<(N_EDGES / 4 + 255) / 256, 256, 0, stream>>>(a1u, outA1);
    combineA0_kernel<<<(N_NODES + 255) / 256, 256, 0, stream>>>(a0c, outA0);
}

// Round 14
// 144.887 us; speedup vs baseline: 1.1338x; 1.1338x over previous
//
#include <hip/hip_runtime.h>

#define N_NODES   100000
#define N_EDGES   1600000
#define N_CLIQUES 250000
#define FIXSCALE  8388608.0f              // 2^23
#define INVSCALE  1.1920928955078125e-7f  // 2^-23

typedef unsigned short ushort8v __attribute__((ext_vector_type(8)));
typedef __bf16 bf16x8 __attribute__((ext_vector_type(8)));
typedef float f32x4 __attribute__((ext_vector_type(4)));
typedef float f32x2 __attribute__((ext_vector_type(2)));

__device__ __forceinline__ float bf2f(unsigned short u) {
    return __uint_as_float(((unsigned int)u) << 16);
}
__device__ __forceinline__ unsigned short f2bf(float f) {
    unsigned int u = __float_as_uint(f);
    u += 0x7FFFu + ((u >> 16) & 1u);
    return (unsigned short)(u >> 16);
}

// ---- prep: W [k][col] f32  ->  wt bf16 [t][col][k] ----
__global__ __launch_bounds__(256) void prep_weights(
    const float* __restrict__ Qw, const float* __restrict__ Kw,
    const float* __restrict__ Vw, unsigned short* __restrict__ wt)
{
    int idx = blockIdx.x * 256 + threadIdx.x;      // 3*128*128 = 49152
    int t = idx >> 14;
    int rem = idx & 16383;
    int col = rem >> 7;
    int k = rem & 127;
    const float* W = (t == 0) ? Qw : ((t == 1) ? Kw : Vw);
    wt[idx] = f2bf(W[k * 128 + col]);              // wt[t][col][k]
}

// ---- Projection via MFMA -> qkv8 fp8-e4m3, FRAGMENT-PERMUTED layout ----
// r10-proven config: 256 threads, 64 nodes/block, no min-waves clause.
// Within each t-region of a node, byte (arow*8 + c) holds output col (c*16+arow).
// Same permutation for q,k,v => the clique contraction (sum over d) is invariant.
__global__ __launch_bounds__(256) void proj_mfma(
    const float* __restrict__ x,
    const unsigned short* __restrict__ wt,   // bf16 [3][col 128][k 128]
    const float* __restrict__ Qb, const float* __restrict__ Kb,
    const float* __restrict__ Vb,
    unsigned char* __restrict__ qkv8)
{
    __shared__ unsigned short wS[128 * 128];  // 32KB W tile, XOR-swizzled chunks

    const int tid  = threadIdx.x;
    const int lane = tid & 63;
    const int w    = tid >> 6;
    const int node0 = blockIdx.x * 64;
    const int arow = lane & 15;
    const int kg   = lane >> 4;

    bf16x8 afrag[4];
    const int myNode = node0 + w * 16 + arow;
    const bool valid = myNode < N_NODES;
    const float* xrow = x + (size_t)myNode * 128;
    #pragma unroll
    for (int kt = 0; kt < 4; ++kt) {
        float4 v0, v1;
        const int kbase = kt * 32 + kg * 8;
        if (valid) {
            v0 = *(const float4*)(xrow + kbase);
            v1 = *(const float4*)(xrow + kbase + 4);
        } else {
            v0.x = v0.y = v0.z = v0.w = 0.f;
            v1.x = v1.y = v1.z = v1.w = 0.f;
        }
        ushort8v u;
        u[0] = f2bf(v0.x); u[1] = f2bf(v0.y); u[2] = f2bf(v0.z); u[3] = f2bf(v0.w);
        u[4] = f2bf(v1.x); u[5] = f2bf(v1.y); u[6] = f2bf(v1.z); u[7] = f2bf(v1.w);
        afrag[kt] = __builtin_bit_cast(bf16x8, u);
    }

    float biasr[3][8];
    #pragma unroll
    for (int t = 0; t < 3; ++t) {
        const float* Bp = (t == 0) ? Qb : ((t == 1) ? Kb : Vb);
        #pragma unroll
        for (int c = 0; c < 8; ++c) biasr[t][c] = Bp[c * 16 + arow];
    }

    for (int t = 0; t < 3; ++t) {
        __syncthreads();
        {
            const unsigned short* src = wt + t * 16384;
            #pragma unroll
            for (int it = 0; it < 8; ++it) {
                int i   = tid + it * 256;
                int col = i >> 4;
                int ko  = i & 15;
                *(ushort8v*)&wS[col * 128 + (ko ^ (col & 7)) * 8] =
                    *(const ushort8v*)(src + i * 8);
            }
        }
        __syncthreads();

        f32x4 acc[8];
        #pragma unroll
        for (int c = 0; c < 8; ++c) acc[c] = (f32x4){0.f, 0.f, 0.f, 0.f};

        #pragma unroll
        for (int kt = 0; kt < 4; ++kt) {
            const int chunk = kt * 4 + kg;
            #pragma unroll
            for (int c = 0; c < 8; ++c) {
                const int col = c * 16 + arow;
                ushort8v bu = *(const ushort8v*)&wS[col * 128 + (chunk ^ (col & 7)) * 8];
                acc[c] = __builtin_amdgcn_mfma_f32_16x16x32_bf16(
                    afrag[kt], __builtin_bit_cast(bf16x8, bu), acc[c], 0, 0, 0);
            }
        }

        #pragma unroll
        for (int r = 0; r < 4; ++r) {
            int node = node0 + w * 16 + kg * 4 + r;
            if (node < N_NODES) {
                int lo0 = __builtin_amdgcn_cvt_pk_fp8_f32(
                    acc[0][r] + biasr[t][0], acc[1][r] + biasr[t][1], 0, false);
                unsigned int w0 = (unsigned int)__builtin_amdgcn_cvt_pk_fp8_f32(
                    acc[2][r] + biasr[t][2], acc[3][r] + biasr[t][3], lo0, true);
                int lo1 = __builtin_amdgcn_cvt_pk_fp8_f32(
                    acc[4][r] + biasr[t][4], acc[5][r] + biasr[t][5], 0, false);
                unsigned int w1 = (unsigned int)__builtin_amdgcn_cvt_pk_fp8_f32(
                    acc[6][r] + biasr[t][6], acc[7][r] + biasr[t][7], lo1, true);
                uint2 o; o.x = w0; o.y = w1;
                *(uint2*)(qkv8 + (size_t)node * 384 + t * 128 + arow * 8) = o;
            }
        }
    }
}

#define DEC4(w_, a_) { f32x2 lo_ = __builtin_amdgcn_cvt_pk_f32_fp8((int)(w_), false); \
                       f32x2 hi_ = __builtin_amdgcn_cvt_pk_f32_fp8((int)(w_), true);  \
                       a_[0] = lo_[0]; a_[1] = lo_[1]; a_[2] = hi_[0]; a_[3] = hi_[1]; }

// ---- Clique contraction (fp8 gather) + fused scatter, ALL-INT atomics ----
// A1: uint fixed-point (750K). A0: uint fixed-point into 8 spread copies
// (1.5M). Measured int RMW rate ~22.3/ns (r13) vs fp32 19.0/ns.
__global__ __launch_bounds__(256) void clique_kernel(
    const unsigned char* __restrict__ qkv8,
    const int* __restrict__ tci,      // [3][N_CLIQUES]
    const int* __restrict__ d1row1,   // [3*N_CLIQUES] clique -> edge ids
    const int* __restrict__ d0row1,   // [2*N_EDGES]   edge -> node ids
    unsigned int* __restrict__ a1u,   // [N_EDGES] fixed-point A1
    float* __restrict__ outA2,
    unsigned int* __restrict__ a0c)   // [8][N_NODES] fixed-point A0
{
    const int tid = threadIdx.x;
    const int lane8 = tid & 7;
    const int cliq = (blockIdx.x * 256 + tid) >> 3;
    if (cliq >= N_CLIQUES) return;

    const int ni = tci[cliq];
    const int nj = tci[N_CLIQUES + cliq];
    const int nk = tci[2 * N_CLIQUES + cliq];
    const int d0 = lane8 * 16;

    const unsigned char* bi = qkv8 + (size_t)ni * 384 + d0;
    const unsigned char* bj = qkv8 + (size_t)nj * 384 + d0;
    const unsigned char* bk = qkv8 + (size_t)nk * 384 + d0;

    const uint4 rQi = *(const uint4*)(bi);
    const uint4 rKi = *(const uint4*)(bi + 128);
    const uint4 rVi = *(const uint4*)(bi + 256);
    const uint4 rQj = *(const uint4*)(bj);
    const uint4 rKj = *(const uint4*)(bj + 128);
    const uint4 rVj = *(const uint4*)(bj + 256);
    const uint4 rQk = *(const uint4*)(bk);
    const uint4 rKk = *(const uint4*)(bk + 128);
    const uint4 rVk = *(const uint4*)(bk + 256);

    float s = 0.f;
    #pragma unroll
    for (int c = 0; c < 4; ++c) {
        unsigned int wQi = ((const unsigned int*)&rQi)[c];
        unsigned int wKi = ((const unsigned int*)&rKi)[c];
        unsigned int wVi = ((const unsigned int*)&rVi)[c];
        unsigned int wQj = ((const unsigned int*)&rQj)[c];
        unsigned int wKj = ((const unsigned int*)&rKj)[c];
        unsigned int wVj = ((const unsigned int*)&rVj)[c];
        unsigned int wQk = ((const unsigned int*)&rQk)[c];
        unsigned int wKk = ((const unsigned int*)&rKk)[c];
        unsigned int wVk = ((const unsigned int*)&rVk)[c];
        float qi_[4], ki_[4], vi_[4], qj_[4], kj_[4], vj_[4], qk_[4], kk_[4], vk_[4];
        DEC4(wQi, qi_); DEC4(wKi, ki_); DEC4(wVi, vi_);
        DEC4(wQj, qj_); DEC4(wKj, kj_); DEC4(wVj, vj_);
        DEC4(wQk, qk_); DEC4(wKk, kk_); DEC4(wVk, vk_);
        #pragma unroll
        for (int d = 0; d < 4; ++d) {
            s = fmaf(qi_[d], fmaf(kj_[d], vk_[d], kk_[d] * vj_[d]), s);
            s = fmaf(qj_[d], fmaf(kk_[d], vi_[d], ki_[d] * vk_[d]), s);
            s = fmaf(qk_[d], fmaf(ki_[d], vj_[d], kj_[d] * vi_[d]), s);
        }
    }
    s += __shfl_xor(s, 1);
    s += __shfl_xor(s, 2);
    s += __shfl_xor(s, 4);

    float score = expf(s * (1.0f / 24.0f));
    if (lane8 == 0) outA2[cliq] = score;
    if (lane8 < 3) {
        int e = d1row1[3 * cliq + lane8];
        unsigned int fx = (unsigned int)__float2uint_rn(score * FIXSCALE);
        atomicAdd(a1u + e, fx);
        int2 tg = *(const int2*)(d0row1 + 2 * (size_t)e);
        unsigned int* base = a0c + (size_t)(cliq & 7) * N_NODES;
        atomicAdd(base + tg.x, fx);
        atomicAdd(base + tg.y, fx);
    }
}

// ---- Decode A1 fixed-point -> float (pure overwrite of outA1) ----
__global__ __launch_bounds__(256) void decodeA1_kernel(
    const unsigned int* __restrict__ a1u, float* __restrict__ outA1)
{
    int e4 = blockIdx.x * 256 + threadIdx.x;     // 400000 threads, 4 edges each
    if (e4 * 4 < N_EDGES) {
        uint4 v = *(const uint4*)(a1u + e4 * 4);
        float4 o;
        o.x = (float)v.x * INVSCALE;
        o.y = (float)v.y * INVSCALE;
        o.z = (float)v.z * INVSCALE;
        o.w = (float)v.w * INVSCALE;
        *(float4*)(outA1 + e4 * 4) = o;
    }
}

// ---- Combine the 8 A0 fixed-point copies, decode to float ----
__global__ __launch_bounds__(256) void combineA0_kernel(
    const unsigned int* __restrict__ a0c, float* __restrict__ outA0)
{
    int n = blockIdx.x * 256 + threadIdx.x;
    if (n < N_NODES) {
        unsigned int s = 0;
        #pragma unroll
        for (int c = 0; c < 8; ++c) s += a0c[(size_t)c * N_NODES + n];
        outA0[n] = (float)s * INVSCALE;
    }
}

extern "C" void kernel_launch(void* const* d_in, const int* in_sizes, int n_in,
                              void* d_out, int out_size, void* d_ws, size_t ws_size,
                              hipStream_t stream)
{
    const float* x  = (const float*)d_in[0];
    const int*   d0i = (const int*)d_in[2];
    const int*   tci = (const int*)d_in[3];
    const int*   d1i = (const int*)d_in[4];
    const float* Qw = (const float*)d_in[5];
    const float* Qb = (const float*)d_in[6];
    const float* Kw = (const float*)d_in[7];
    const float* Kb = (const float*)d_in[8];
    const float* Vw = (const float*)d_in[9];
    const float* Vb = (const float*)d_in[10];

    const int* d0row1 = d0i + 2 * (size_t)N_EDGES;
    const int* d1row1 = d1i + 3 * (size_t)N_CLIQUES;

    // ws: qkv8 38.4MB | wt 96KB | a1u u32 6.4MB | a0c u32 [8][N_NODES] 3.2MB
    const size_t QKV_B = (size_t)N_NODES * 384;
    const size_t WT_B  = 3 * 128 * 128 * 2;
    const size_t A1U_B = (size_t)N_EDGES * 4;
    unsigned char* qkv8 = (unsigned char*)d_ws;
    unsigned short* wt  = (unsigned short*)(qkv8 + QKV_B);
    unsigned int* a1u = (unsigned int*)(qkv8 + QKV_B + WT_B);
    unsigned int* a0c = (unsigned int*)(qkv8 + QKV_B + WT_B + A1U_B);

    // outputs: FLOAT32, concatenated (diagA0, diagA1, diagA2)
    float* outA0 = (float*)d_out;
    float* outA1 = outA0 + N_NODES;
    float* outA2 = outA0 + N_NODES + N_EDGES;

    hipMemsetAsync(a1u, 0, A1U_B, stream);
    hipMemsetAsync(a0c, 0, (size_t)8 * N_NODES * 4, stream);
    prep_weights<<<192, 256, 0, stream>>>(Qw, Kw, Vw, wt);
    proj_mfma<<<(N_NODES + 63) / 64, 256, 0, stream>>>(x, wt, Qb, Kb, Vb, qkv8);
    clique_kernel<<<(N_CLIQUES * 8 + 255) / 256, 256, 0, stream>>>(
        qkv8, tci, d1row1, d0row1, a1u, outA2, a0c);
    decodeA1_kernel<<<(N_EDGES / 4 + 255) / 256, 256, 0, stream>>>(a1u, outA1);
    combineA0_kernel<<<(N_NODES + 255) / 256, 256, 0, stream>>>(a0c, outA0);
}